// Round 5
// baseline (1140.083 us; speedup 1.0000x reference)
//
#include <hip/hip_runtime.h>
#include <stdint.h>

// TreeCRF sum-product BP -- DIAGNOSTIC ROUND.
// Identical structure to R4 (5 dispatches), but the two dominant kernels are
// repeated (idempotently) so they exceed the harness's 330us poison fills and
// surface in the rocprof top-5 with full counters:
//   up_sub bottom:  REPEAT=4  (pure function of unary/ep -> rewrite same values)
//   down_sub bottom: REPEAT=10 (early iters write beliefs to ws scratch; the
//                    final iter writes d_out; subtotals in d_out stay intact
//                    until the final iteration, so every iter computes the
//                    same beliefs)
// Read: up1 = dur(up<4>)/4, down1 = dur(down<10>)/10; hbm_gbps/VALUBusy/
// OccupancyPercent tell us latency- vs compute- vs BW-bound; down FETCH tells
// us whether e8 is L3-resident (informs fusion next round).

#ifndef __has_builtin
#define __has_builtin(x) 0
#endif
#if __has_builtin(__builtin_amdgcn_cvt_pk_fp8_f32) && __has_builtin(__builtin_amdgcn_cvt_f32_fp8)
#define EP8_FP8 1
#define EPC_BYTES 256   // 16x16 fp8
#else
#define EP8_FP8 0
#define EPC_BYTES 512   // 16x16 bf16 fallback
#endif

__device__ __forceinline__ void ldvec16(const float* p, float* d) {
    const float4* q = (const float4*)p;
    #pragma unroll
    for (int t = 0; t < 4; ++t) {
        float4 a = q[t];
        d[4*t+0] = a.x; d[4*t+1] = a.y; d[4*t+2] = a.z; d[4*t+3] = a.w;
    }
}

__device__ __forceinline__ float lse16_rs(const float* r, const float* s) {
    float v[16];
    float m;
    #pragma unroll
    for (int j = 0; j < 16; ++j) {
        v[j] = r[j] + s[j];
        m = (j == 0) ? v[0] : fmaxf(m, v[j]);
    }
    float acc = 0.f;
    #pragma unroll
    for (int j = 0; j < 16; ++j) acc += __expf(v[j] - m);
    return m + __logf(acc);
}

__device__ __forceinline__ void enc_row(uint8_t* dst, const float* r) {
#if EP8_FP8
    int w[4];
    #pragma unroll
    for (int t = 0; t < 4; ++t) {
        int x = __builtin_amdgcn_cvt_pk_fp8_f32(r[4*t+0], r[4*t+1], 0, false);
        x     = __builtin_amdgcn_cvt_pk_fp8_f32(r[4*t+2], r[4*t+3], x, true);
        w[t] = x;
    }
    *(int4*)dst = make_int4(w[0], w[1], w[2], w[3]);
#else
    uint32_t w[8];
    #pragma unroll
    for (int t = 0; t < 8; ++t) {
        uint32_t lo = __float_as_uint(r[2*t+0]);
        uint32_t hi = __float_as_uint(r[2*t+1]);
        w[t] = (lo >> 16) | (hi & 0xffff0000u);
    }
    ((int4*)dst)[0] = make_int4(w[0], w[1], w[2], w[3]);
    ((int4*)dst)[1] = make_int4(w[4], w[5], w[6], w[7]);
#endif
}

__device__ __forceinline__ void dec_row(const uint8_t* src, float* r) {
#if EP8_FP8
    uint4 w = *(const uint4*)src;
    uint32_t ws[4] = {w.x, w.y, w.z, w.w};
    #pragma unroll
    for (int t = 0; t < 4; ++t) {
        uint32_t u = ws[t];
        r[4*t+0] = __builtin_amdgcn_cvt_f32_fp8(u, 0);
        r[4*t+1] = __builtin_amdgcn_cvt_f32_fp8(u, 1);
        r[4*t+2] = __builtin_amdgcn_cvt_f32_fp8(u, 2);
        r[4*t+3] = __builtin_amdgcn_cvt_f32_fp8(u, 3);
    }
#else
    uint4 w0 = ((const uint4*)src)[0];
    uint4 w1 = ((const uint4*)src)[1];
    uint32_t ws[8] = {w0.x, w0.y, w0.z, w0.w, w1.x, w1.y, w1.z, w1.w};
    #pragma unroll
    for (int t = 0; t < 8; ++t) {
        r[2*t+0] = __uint_as_float(ws[t] << 16);
        r[2*t+1] = __uint_as_float(ws[t] & 0xffff0000u);
    }
#endif
}

__device__ __forceinline__ float dec_elem(const uint8_t* nodebase, int k, int i) {
#if EP8_FP8
    return __builtin_amdgcn_cvt_f32_fp8((uint32_t)nodebase[k*16 + i], 0);
#else
    uint32_t u = ((const uint16_t*)nodebase)[k*16 + i];
    return __uint_as_float(u << 16);
#endif
}

// ================= chunked subtree kernels =================
template <bool USE8, int REPEAT>
__global__ __launch_bounds__(256) void up_sub(
    const float* __restrict__ unary, const float* __restrict__ ep,
    float* __restrict__ out, uint8_t* __restrict__ e8,
    int rl, int dl, int depth) {
    __shared__ float sub[2][32][16];
    int j = blockIdx.x;
    for (int rep = 0; rep < REPEAT; ++rep) {
        int cur = 0;
        for (int d = dl; d > rl; --d) {
            int np = 1 << (d - 1 - rl);
            size_t pbase = (((size_t)1 << (d - 1)) - 1) + (size_t)j * np;
            bool fromGlobal = (d == dl);
            const float* gsrc = (d == depth) ? unary : out;
            for (int t = threadIdx.x; t < np * 16; t += 256) {
                int pl = t >> 4, i = t & 15;
                size_t p = pbase + pl;
                size_t cl = 2 * p + 1, cr = cl + 1;
                float s[16], r[16];

                if (fromGlobal) ldvec16(gsrc + cl * 16, s);
                else            ldvec16(&sub[cur ^ 1][2 * pl][0], s);
                ldvec16(ep + (cl - 1) * 256 + i * 16, r);
                float msgL = lse16_rs(r, s);
                if (USE8) enc_row(e8 + (cl - 1) * EPC_BYTES + i * (EPC_BYTES / 16), r);

                if (fromGlobal) ldvec16(gsrc + cr * 16, s);
                else            ldvec16(&sub[cur ^ 1][2 * pl + 1][0], s);
                ldvec16(ep + (cr - 1) * 256 + i * 16, r);
                float msgR = lse16_rs(r, s);
                if (USE8) enc_row(e8 + (cr - 1) * EPC_BYTES + i * (EPC_BYTES / 16), r);

                float v = unary[p * 16 + i] + msgL + msgR;
                out[p * 16 + i] = v;
                if (d - 1 > rl) sub[cur][pl][i] = v;
            }
            __syncthreads();
            cur ^= 1;
        }
        __syncthreads();
    }
}

// dst_final = out on the last repeat; dst_scratch earlier (identical values).
template <bool USE8, int REPEAT>
__global__ __launch_bounds__(256) void down_sub(
    const float* __restrict__ unary, const float* __restrict__ ep,
    const uint8_t* __restrict__ e8, float* __restrict__ out,
    float* __restrict__ scratch, int rl, int dl, int depth) {
    __shared__ float bel[2][32][16];
    int j = blockIdx.x;
    for (int rep = 0; rep < REPEAT; ++rep) {
        float* dst = (rep == REPEAT - 1) ? out : scratch;
        int cur = 0;
        for (int d = rl + 1; d <= dl; ++d) {
            int nc = 1 << (d - rl);
            size_t cbase = (((size_t)1 << d) - 1) + (size_t)j * nc;
            bool leaf = (d == depth);
            bool parGlobal = (d == rl + 1);
            for (int t = threadIdx.x; t < nc * 16; t += 256) {
                int vl = t >> 4, i = t & 15;
                size_t v = cbase + vl;
                const float* ssrc = leaf ? unary : out;
                float s[16], r[16];
                ldvec16(ssrc + v * 16, s);
                float sub_i = ssrc[v * 16 + i];

                if (USE8) dec_row(e8 + (v - 1) * EPC_BYTES + i * (EPC_BYTES / 16), r);
                else      ldvec16(ep + (v - 1) * 256 + i * 16, r);
                float mup = lse16_rs(r, s);

                float pt;
                if (parGlobal) pt = out[((v - 1) >> 1) * 16 + i];
                else           pt = bel[cur ^ 1][vl >> 1][i];
                float v2f = pt - mup;

                float c[16];
                if (USE8) {
                    const uint8_t* nb = e8 + (v - 1) * EPC_BYTES;
                    #pragma unroll
                    for (int k = 0; k < 16; ++k) c[k] = dec_elem(nb, k, i);
                } else {
                    const float* nb = ep + (v - 1) * 256 + i;
                    #pragma unroll
                    for (int k = 0; k < 16; ++k) c[k] = nb[k * 16];
                }

                float vv[16], m;
                #pragma unroll
                for (int k = 0; k < 16; ++k) {
                    float x = c[k] + __shfl(v2f, k, 16);
                    vv[k] = x;
                    m = (k == 0) ? x : fmaxf(m, x);
                }
                float acc = 0.f;
                #pragma unroll
                for (int k = 0; k < 16; ++k) acc += __expf(vv[k] - m);
                float msg = m + __logf(acc);

                float b = sub_i + msg;
                dst[v * 16 + i] = b;
                if (d < dl) bel[cur][vl][i] = b;
            }
            __syncthreads();
            cur ^= 1;
        }
        __syncthreads();
    }
}

// ================= fused top of tree (fp32 ep) =================
__device__ __forceinline__ void up_body_f32(const float* __restrict__ unary,
                                            const float* __restrict__ ep,
                                            float* out, size_t p, int i) {
    size_t cl = 2 * p + 1, cr = cl + 1;
    float s[16], r[16];
    ldvec16(out + cl * 16, s);
    ldvec16(ep + (cl - 1) * 256 + i * 16, r);
    float msgL = lse16_rs(r, s);
    ldvec16(out + cr * 16, s);
    ldvec16(ep + (cr - 1) * 256 + i * 16, r);
    float msgR = lse16_rs(r, s);
    out[p * 16 + i] = unary[p * 16 + i] + msgL + msgR;
}

__device__ __forceinline__ void down_body_f32(const float* __restrict__ ep,
                                              float* out, size_t v, int i) {
    size_t par = (v - 1) >> 1;
    float s[16], r[16];
    ldvec16(out + v * 16, s);
    float sub_i = out[v * 16 + i];
    ldvec16(ep + (v - 1) * 256 + i * 16, r);
    float mup = lse16_rs(r, s);
    float v2f = out[par * 16 + i] - mup;
    const float* nb = ep + (v - 1) * 256 + i;
    float c[16];
    #pragma unroll
    for (int k = 0; k < 16; ++k) c[k] = nb[k * 16];
    float vv[16], m;
    #pragma unroll
    for (int k = 0; k < 16; ++k) {
        float x = c[k] + __shfl(v2f, k, 16);
        vv[k] = x;
        m = (k == 0) ? x : fmaxf(m, x);
    }
    float acc = 0.f;
    #pragma unroll
    for (int k = 0; k < 16; ++k) acc += __expf(vv[k] - m);
    out[v * 16 + i] = sub_i + m + __logf(acc);
}

__global__ __launch_bounds__(1024) void top_fused(const float* __restrict__ unary,
                                                  const float* __restrict__ ep,
                                                  float* out, int FD) {
    int tid = threadIdx.x;
    for (int d = FD; d >= 1; --d) {
        int pcount = 1 << (d - 1);
        size_t plo = pcount - 1;
        for (int t = tid; t < pcount * 16; t += blockDim.x)
            up_body_f32(unary, ep, out, plo + (t >> 4), t & 15);
        __syncthreads();
    }
    for (int d = 1; d <= FD; ++d) {
        int count = 1 << d;
        size_t lo = count - 1;
        for (int t = tid; t < count * 16; t += blockDim.x)
            down_body_f32(ep, out, lo + (t >> 4), t & 15);
        __syncthreads();
    }
}

extern "C" void kernel_launch(void* const* d_in, const int* in_sizes, int n_in,
                              void* d_out, int out_size, void* d_ws, size_t ws_size,
                              hipStream_t stream) {
    const float* unary = (const float*)d_in[0];
    const float* ep    = (const float*)d_in[1];
    float* out = (float*)d_out;
    uint8_t* e8 = (uint8_t*)d_ws;

    int Nn = in_sizes[0] / 16;
    int depth = 0;
    while ((1 << (depth + 1)) < Nn + 1) ++depth;

    size_t e8_bytes = (size_t)(Nn - 1) * EPC_BYTES;
    size_t scratch_off = (e8_bytes + 255) & ~(size_t)255;
    size_t out_bytes = (size_t)Nn * 16 * sizeof(float);
    bool use8 = ws_size >= scratch_off + out_bytes;   // need e8 + belief scratch
    float* scratch = (float*)((uint8_t*)d_ws + scratch_off);

    int rls[8], dls[8], nch = 0;
    int dl = depth;
    if (depth > 6) {
        while (dl > 6) { rls[nch] = dl - 6; dls[nch] = dl; ++nch; dl -= 6; }
    } else {
        rls[0] = 0; dls[0] = depth; nch = 1; dl = 0;
    }
    int FD = dl;

    for (int c = 0; c < nch; ++c) {
        dim3 grid(1u << rls[c]), block(256);
        bool bottom = (dls[c] == depth);
        if (use8) {
            if (bottom) up_sub<true, 4><<<grid, block, 0, stream>>>(unary, ep, out, e8, rls[c], dls[c], depth);
            else        up_sub<true, 1><<<grid, block, 0, stream>>>(unary, ep, out, e8, rls[c], dls[c], depth);
        } else {
            up_sub<false, 1><<<grid, block, 0, stream>>>(unary, ep, out, e8, rls[c], dls[c], depth);
        }
    }
    if (FD > 0)
        top_fused<<<1, 1024, 0, stream>>>(unary, ep, out, FD);
    for (int c = nch - 1; c >= 0; --c) {
        dim3 grid(1u << rls[c]), block(256);
        bool bottom = (dls[c] == depth);
        if (use8) {
            if (bottom) down_sub<true, 10><<<grid, block, 0, stream>>>(unary, ep, e8, out, scratch, rls[c], dls[c], depth);
            else        down_sub<true, 1 ><<<grid, block, 0, stream>>>(unary, ep, e8, out, scratch, rls[c], dls[c], depth);
        } else {
            down_sub<false, 1><<<grid, block, 0, stream>>>(unary, ep, e8, out, scratch, rls[c], dls[c], depth);
        }
    }
}

// Round 6
// 249.914 us; speedup vs baseline: 4.5619x; 4.5619x over previous
//
#include <hip/hip_runtime.h>
#include <stdint.h>

// TreeCRF sum-product BP, complete binary tree, C=16, fp32 in/out.
//
// R6 structure (15 dispatches at depth=18):
//   up_flat<true>  d=18..13   (flat per-level; 98.4% of edges)
//   up_sub_f32     levels 12..7 chunked (64 blocks)
//   top_fused      levels 6..1 up + 1..6 down (1 block)
//   down_sub_f32   levels 7..12 chunked
//   down_flat<true> d=13..18  (flat per-level)
//
// Exp-domain trick: up pass computes E = exp(ep) for its own LSE (FMA form:
// msg = log(sum E[i][j]*exp(sub[j]-m)) + m), quantizes E to fp8 e4m3 in d_ws,
// and stores m_up as bf16. Down pass then needs only:
//   u[k] = exp(v2f[k]-m);  msg[i] = log(sum_k E[k][i]*u[k]) + m
// = 1 exp + 1 log per thread (was 33 transcendentals), E row read as one
// uint4, column-sum via LDS 16x16 transpose (pad 20 floats -> 2-way banks).

#define EPC 256   // bytes per node in e8 copy (16x16 fp8)

__device__ __forceinline__ void ldvec16(const float* p, float* d) {
    const float4* q = (const float4*)p;
    #pragma unroll
    for (int t = 0; t < 4; ++t) {
        float4 a = q[t];
        d[4*t+0] = a.x; d[4*t+1] = a.y; d[4*t+2] = a.z; d[4*t+3] = a.w;
    }
}

// log-domain logsumexp_j( r[j] + s[j] )  (fp32 paths)
__device__ __forceinline__ float lse16_rs(const float* r, const float* s) {
    float v[16];
    float m;
    #pragma unroll
    for (int j = 0; j < 16; ++j) {
        v[j] = r[j] + s[j];
        m = (j == 0) ? v[0] : fmaxf(m, v[j]);
    }
    float acc = 0.f;
    #pragma unroll
    for (int j = 0; j < 16; ++j) acc += __expf(v[j] - m);
    return m + __logf(acc);
}

__device__ __forceinline__ void enc_row(uint8_t* dst, const float* E) {
    int w[4];
    #pragma unroll
    for (int t = 0; t < 4; ++t) {
        int x = __builtin_amdgcn_cvt_pk_fp8_f32(E[4*t+0], E[4*t+1], 0, false);
        x     = __builtin_amdgcn_cvt_pk_fp8_f32(E[4*t+2], E[4*t+3], x, true);
        w[t] = x;
    }
    *(int4*)dst = make_int4(w[0], w[1], w[2], w[3]);
}

__device__ __forceinline__ void dec_row(const uint8_t* src, float* E) {
    uint4 w = *(const uint4*)src;
    uint32_t a;
    a = w.x;
    E[0]  = __builtin_amdgcn_cvt_f32_fp8(a, 0);
    E[1]  = __builtin_amdgcn_cvt_f32_fp8(a, 1);
    E[2]  = __builtin_amdgcn_cvt_f32_fp8(a, 2);
    E[3]  = __builtin_amdgcn_cvt_f32_fp8(a, 3);
    a = w.y;
    E[4]  = __builtin_amdgcn_cvt_f32_fp8(a, 0);
    E[5]  = __builtin_amdgcn_cvt_f32_fp8(a, 1);
    E[6]  = __builtin_amdgcn_cvt_f32_fp8(a, 2);
    E[7]  = __builtin_amdgcn_cvt_f32_fp8(a, 3);
    a = w.z;
    E[8]  = __builtin_amdgcn_cvt_f32_fp8(a, 0);
    E[9]  = __builtin_amdgcn_cvt_f32_fp8(a, 1);
    E[10] = __builtin_amdgcn_cvt_f32_fp8(a, 2);
    E[11] = __builtin_amdgcn_cvt_f32_fp8(a, 3);
    a = w.w;
    E[12] = __builtin_amdgcn_cvt_f32_fp8(a, 0);
    E[13] = __builtin_amdgcn_cvt_f32_fp8(a, 1);
    E[14] = __builtin_amdgcn_cvt_f32_fp8(a, 2);
    E[15] = __builtin_amdgcn_cvt_f32_fp8(a, 3);
}

__device__ __forceinline__ uint16_t f32_to_bf16(float x) {
    uint32_t u = __float_as_uint(x);
    u += 0x7fff + ((u >> 16) & 1);      // round-to-nearest-even
    return (uint16_t)(u >> 16);
}
__device__ __forceinline__ float bf16_to_f32(uint16_t h) {
    return __uint_as_float((uint32_t)h << 16);
}

// ================= flat per-level kernels (bulk levels) =================
// up_flat: child level d; parents plo..plo+pcount. USE8: exp-domain + store
// E(fp8) and m_up(bf16). csrc = child subtotal array (unary at leaf level).
template <bool USE8>
__global__ __launch_bounds__(256) void up_flat(
    const float* __restrict__ csrc, const float* __restrict__ unary,
    const float* __restrict__ ep, float* __restrict__ out,
    uint8_t* __restrict__ e8, uint16_t* __restrict__ mup,
    int plo, int pcount) {
    int t = blockIdx.x * 256 + threadIdx.x;
    if (t >= pcount * 16) return;
    int i = t & 15;
    size_t p = (size_t)plo + (t >> 4);
    size_t cl = 2 * p + 1;

    float msg[2];
    #pragma unroll
    for (int ch = 0; ch < 2; ++ch) {
        size_t c = cl + ch;
        float s[16], r[16];
        ldvec16(csrc + c * 16, s);
        ldvec16(ep + (c - 1) * 256 + i * 16, r);
        if (USE8) {
            float E[16];
            #pragma unroll
            for (int j = 0; j < 16; ++j) E[j] = __expf(r[j]);
            enc_row(e8 + (c - 1) * EPC + i * 16, E);
            float m = s[0];
            #pragma unroll
            for (int j = 1; j < 16; ++j) m = fmaxf(m, s[j]);
            float acc = 0.f;
            #pragma unroll
            for (int j = 0; j < 16; ++j) acc += E[j] * __expf(s[j] - m);
            msg[ch] = __logf(acc) + m;
            mup[c * 16 + i] = f32_to_bf16(msg[ch]);
        } else {
            msg[ch] = lse16_rs(r, s);
        }
    }
    out[p * 16 + i] = unary[p * 16 + i] + msg[0] + msg[1];
}

// down_flat: node level d (lo..lo+count). USE8: exp-domain with stored E/mup,
// LDS 16x16 transpose-sum. ssrc = subtotal source (unary at leaves else out).
template <bool USE8>
__global__ __launch_bounds__(256) void down_flat(
    const float* __restrict__ ssrc, const float* __restrict__ ep,
    const uint8_t* __restrict__ e8, const uint16_t* __restrict__ mup,
    float* __restrict__ out, int lo, int count) {
    if (!USE8) {
        // fp32 log-domain fallback (no barrier; guarded)
        int t = blockIdx.x * 256 + threadIdx.x;
        if (t >= count * 16) return;
        int i = t & 15;
        size_t v = (size_t)lo + (t >> 4);
        size_t par = (v - 1) >> 1;
        float s[16], r[16];
        ldvec16(ssrc + v * 16, s);
        float sub_i = ssrc[v * 16 + i];
        ldvec16(ep + (v - 1) * 256 + i * 16, r);
        float mu = lse16_rs(r, s);
        float v2f = out[par * 16 + i] - mu;
        const float* nb = ep + (v - 1) * 256 + i;
        float c[16];
        #pragma unroll
        for (int k = 0; k < 16; ++k) c[k] = nb[k * 16];
        float vv[16], m;
        #pragma unroll
        for (int k = 0; k < 16; ++k) {
            float x = c[k] + __shfl(v2f, k, 16);
            vv[k] = x;
            m = (k == 0) ? x : fmaxf(m, x);
        }
        float acc = 0.f;
        #pragma unroll
        for (int k = 0; k < 16; ++k) acc += __expf(vv[k] - m);
        out[v * 16 + i] = sub_i + m + __logf(acc);
        return;
    }
    // USE8 path: requires count*16 % 256 == 0 (full blocks; levels >= 4).
    __shared__ float T[16][16][20];     // [group][row][col+pad]
    int g = threadIdx.x >> 4, i = threadIdx.x & 15;
    size_t v = (size_t)lo + (size_t)(blockIdx.x * 16 + g);
    size_t par = (v - 1) >> 1;

    float sub_i = ssrc[v * 16 + i];
    float pt    = out[par * 16 + i];
    float mu    = bf16_to_f32(mup[v * 16 + i]);
    float v2f   = pt - mu;

    float m = v2f;
    m = fmaxf(m, __shfl_xor(m, 1, 16));
    m = fmaxf(m, __shfl_xor(m, 2, 16));
    m = fmaxf(m, __shfl_xor(m, 4, 16));
    m = fmaxf(m, __shfl_xor(m, 8, 16));
    float u = __expf(v2f - m);

    float E[16];
    dec_row(e8 + (v - 1) * EPC + i * 16, E);
    #pragma unroll
    for (int j = 0; j < 16; ++j) T[g][i][j] = E[j] * u;
    __syncthreads();
    float acc = 0.f;
    #pragma unroll
    for (int k = 0; k < 16; ++k) acc += T[g][k][i];

    out[v * 16 + i] = sub_i + __logf(acc) + m;
}

// ================= chunked fp32 kernels (mid levels 7..12) =================
__global__ __launch_bounds__(256) void up_sub_f32(
    const float* __restrict__ unary, const float* __restrict__ ep,
    float* __restrict__ out, int rl, int dl, int depth) {
    __shared__ float sub[2][32][16];
    int j = blockIdx.x;
    int cur = 0;
    for (int d = dl; d > rl; --d) {
        int np = 1 << (d - 1 - rl);
        size_t pbase = (((size_t)1 << (d - 1)) - 1) + (size_t)j * np;
        bool fromGlobal = (d == dl);
        const float* gsrc = (d == depth) ? unary : out;
        for (int t = threadIdx.x; t < np * 16; t += 256) {
            int pl = t >> 4, i = t & 15;
            size_t p = pbase + pl;
            size_t cl = 2 * p + 1, cr = cl + 1;
            float s[16], r[16];

            if (fromGlobal) ldvec16(gsrc + cl * 16, s);
            else            ldvec16(&sub[cur ^ 1][2 * pl][0], s);
            ldvec16(ep + (cl - 1) * 256 + i * 16, r);
            float msgL = lse16_rs(r, s);

            if (fromGlobal) ldvec16(gsrc + cr * 16, s);
            else            ldvec16(&sub[cur ^ 1][2 * pl + 1][0], s);
            ldvec16(ep + (cr - 1) * 256 + i * 16, r);
            float msgR = lse16_rs(r, s);

            float v = unary[p * 16 + i] + msgL + msgR;
            out[p * 16 + i] = v;
            if (d - 1 > rl) sub[cur][pl][i] = v;
        }
        __syncthreads();
        cur ^= 1;
    }
}

__global__ __launch_bounds__(256) void down_sub_f32(
    const float* __restrict__ unary, const float* __restrict__ ep,
    float* __restrict__ out, int rl, int dl, int depth) {
    __shared__ float bel[2][32][16];
    int j = blockIdx.x;
    int cur = 0;
    for (int d = rl + 1; d <= dl; ++d) {
        int nc = 1 << (d - rl);
        size_t cbase = (((size_t)1 << d) - 1) + (size_t)j * nc;
        bool leaf = (d == depth);
        bool parGlobal = (d == rl + 1);
        for (int t = threadIdx.x; t < nc * 16; t += 256) {
            int vl = t >> 4, i = t & 15;
            size_t v = cbase + vl;
            const float* ssrc = leaf ? unary : out;
            float s[16], r[16];
            ldvec16(ssrc + v * 16, s);
            float sub_i = ssrc[v * 16 + i];
            ldvec16(ep + (v - 1) * 256 + i * 16, r);
            float mu = lse16_rs(r, s);

            float pt;
            if (parGlobal) pt = out[((v - 1) >> 1) * 16 + i];
            else           pt = bel[cur ^ 1][vl >> 1][i];
            float v2f = pt - mu;

            const float* nb = ep + (v - 1) * 256 + i;
            float c[16];
            #pragma unroll
            for (int k = 0; k < 16; ++k) c[k] = nb[k * 16];

            float vv[16], m;
            #pragma unroll
            for (int k = 0; k < 16; ++k) {
                float x = c[k] + __shfl(v2f, k, 16);
                vv[k] = x;
                m = (k == 0) ? x : fmaxf(m, x);
            }
            float acc = 0.f;
            #pragma unroll
            for (int k = 0; k < 16; ++k) acc += __expf(vv[k] - m);
            float b = sub_i + m + __logf(acc);
            out[v * 16 + i] = b;
            if (d < dl) bel[cur][vl][i] = b;
        }
        __syncthreads();
        cur ^= 1;
    }
}

// ================= fused top of tree (levels 1..FD, fp32) =================
__device__ __forceinline__ void up_body_f32(const float* __restrict__ unary,
                                            const float* __restrict__ ep,
                                            float* out, size_t p, int i) {
    size_t cl = 2 * p + 1, cr = cl + 1;
    float s[16], r[16];
    ldvec16(out + cl * 16, s);
    ldvec16(ep + (cl - 1) * 256 + i * 16, r);
    float msgL = lse16_rs(r, s);
    ldvec16(out + cr * 16, s);
    ldvec16(ep + (cr - 1) * 256 + i * 16, r);
    float msgR = lse16_rs(r, s);
    out[p * 16 + i] = unary[p * 16 + i] + msgL + msgR;
}

__device__ __forceinline__ void down_body_f32(const float* __restrict__ ep,
                                              float* out, size_t v, int i) {
    size_t par = (v - 1) >> 1;
    float s[16], r[16];
    ldvec16(out + v * 16, s);
    float sub_i = out[v * 16 + i];
    ldvec16(ep + (v - 1) * 256 + i * 16, r);
    float mu = lse16_rs(r, s);
    float v2f = out[par * 16 + i] - mu;
    const float* nb = ep + (v - 1) * 256 + i;
    float c[16];
    #pragma unroll
    for (int k = 0; k < 16; ++k) c[k] = nb[k * 16];
    float vv[16], m;
    #pragma unroll
    for (int k = 0; k < 16; ++k) {
        float x = c[k] + __shfl(v2f, k, 16);
        vv[k] = x;
        m = (k == 0) ? x : fmaxf(m, x);
    }
    float acc = 0.f;
    #pragma unroll
    for (int k = 0; k < 16; ++k) acc += __expf(vv[k] - m);
    out[v * 16 + i] = sub_i + m + __logf(acc);
}

__global__ __launch_bounds__(1024) void top_fused(const float* __restrict__ unary,
                                                  const float* __restrict__ ep,
                                                  float* out, int FD) {
    int tid = threadIdx.x;
    for (int d = FD; d >= 1; --d) {
        int pcount = 1 << (d - 1);
        size_t plo = pcount - 1;
        for (int t = tid; t < pcount * 16; t += blockDim.x)
            up_body_f32(unary, ep, out, plo + (t >> 4), t & 15);
        __syncthreads();
    }
    for (int d = 1; d <= FD; ++d) {
        int count = 1 << d;
        size_t lo = count - 1;
        for (int t = tid; t < count * 16; t += blockDim.x)
            down_body_f32(ep, out, lo + (t >> 4), t & 15);
        __syncthreads();
    }
}

extern "C" void kernel_launch(void* const* d_in, const int* in_sizes, int n_in,
                              void* d_out, int out_size, void* d_ws, size_t ws_size,
                              hipStream_t stream) {
    const float* unary = (const float*)d_in[0];
    const float* ep    = (const float*)d_in[1];
    float* out = (float*)d_out;

    int Nn = in_sizes[0] / 16;
    int depth = 0;
    while ((1 << (depth + 1)) < Nn + 1) ++depth;   // Nn + 1 == 2^(depth+1)

    uint8_t* e8 = (uint8_t*)d_ws;
    size_t e8_bytes = (size_t)Nn * EPC;
    size_t mup_off = (e8_bytes + 255) & ~(size_t)255;
    uint16_t* mup = (uint16_t*)((uint8_t*)d_ws + mup_off);
    size_t need = mup_off + (size_t)Nn * 16 * 2;
    bool use8 = ws_size >= need;

    if (use8 && depth >= 13) {
        // --- main path (depth=18 case) ---
        for (int d = depth; d >= 13; --d) {
            int pcount = 1 << (d - 1);
            int plo = pcount - 1;
            const float* csrc = (d == depth) ? unary : out;
            up_flat<true><<<pcount * 16 / 256, 256, 0, stream>>>(
                csrc, unary, ep, out, e8, mup, plo, pcount);
        }
        up_sub_f32<<<64, 256, 0, stream>>>(unary, ep, out, 6, 12, depth);
        top_fused<<<1, 1024, 0, stream>>>(unary, ep, out, 6);
        down_sub_f32<<<64, 256, 0, stream>>>(unary, ep, out, 6, 12, depth);
        for (int d = 13; d <= depth; ++d) {
            int count = 1 << d;
            int lo = count - 1;
            const float* ssrc = (d == depth) ? unary : out;
            down_flat<true><<<count * 16 / 256, 256, 0, stream>>>(
                ssrc, ep, e8, mup, out, lo, count);
        }
    } else {
        // --- generic fp32 fallback: flat levels + fused top ---
        int FD = (depth >= 2) ? ((depth - 1 < 6) ? depth - 1 : 6) : 0;
        for (int d = depth; d > FD; --d) {
            int pcount = 1 << (d - 1);
            int plo = pcount - 1;
            const float* csrc = (d == depth) ? unary : out;
            dim3 grid((pcount * 16 + 255) / 256);
            up_flat<false><<<grid, 256, 0, stream>>>(
                csrc, unary, ep, out, e8, mup, plo, pcount);
        }
        if (FD > 0)
            top_fused<<<1, 1024, 0, stream>>>(unary, ep, out, FD);
        for (int d = FD + 1; d <= depth; ++d) {
            int count = 1 << d;
            int lo = count - 1;
            const float* ssrc = (d == depth) ? unary : out;
            dim3 grid((count * 16 + 255) / 256);
            down_flat<false><<<grid, 256, 0, stream>>>(
                ssrc, ep, e8, mup, out, lo, count);
        }
    }
}